// Round 11
// baseline (392.017 us; speedup 1.0000x reference)
//
#include <hip/hip_runtime.h>
#include <hip/hip_bf16.h>
#include <cstdint>
#include <cstddef>

// Shapes: B=2, S=512, C=25, H=768, 2H=1536, 3H=2304, 4H=3072
#define BB 2
#define SS 512
#define CC 25
#define HH 768
#define H2 1536
#define H3 2304
#define H4 3072
// chunked layout: [kc][row][8] bf16, kc = k/8
#define XC_STRIDE ((size_t)96 * 512 * 8)   // per-bc X slab, 96 chunks x 512 rows

typedef __attribute__((ext_vector_type(8))) short bf16x8;
typedef __attribute__((ext_vector_type(4))) float f32x4;

#define DEVINL static __device__ __forceinline__

DEVINL unsigned short f2bf(float f) {
  union { float f; unsigned u; } v; v.f = f;
  unsigned r = v.u + 0x7FFF + ((v.u >> 16) & 1);  // RNE
  return (unsigned short)(r >> 16);
}
DEVINL float bf2f(unsigned short b) {
  union { unsigned u; float f; } v; v.u = ((unsigned)b) << 16; return v.f;
}

DEVINL void async16(const void* g, void* l) {
  __builtin_amdgcn_global_load_lds(
      (const __attribute__((address_space(1))) void*)g,
      (__attribute__((address_space(3))) void*)l, 16, 0, 0);
}

// ---------------- K1: all casts/chunking + out init (5316 blocks) ----------
__global__ void k_prep(const float* __restrict__ token,
                       const float* __restrict__ label,
                       const float* __restrict__ b2,
                       const float* __restrict__ Wt,
                       const float* __restrict__ Wl,
                       const float* __restrict__ W1,
                       unsigned short* __restrict__ TC,
                       unsigned short* __restrict__ LC,
                       float* __restrict__ out,
                       unsigned short* __restrict__ WtC,
                       unsigned short* __restrict__ WlC,
                       unsigned short* __restrict__ W1C) {
  __shared__ float tile[64][33];
  const int bid = blockIdx.x;
  const int tid = threadIdx.x;
  if (bid < 408) {
    const float* in;
    unsigned short* o;
    int R, RP, kt, rt;
    if (bid < 384) {
      in = token; o = TC; R = 1024; RP = 1024; kt = bid % 24; rt = bid / 24;
    } else {
      in = label; o = LC; R = 50; RP = 64; kt = bid - 384; rt = 0;
    }
    const int k0 = kt * 32, r0 = rt * 64;
    const int tx = tid & 31, ty = tid >> 5;
#pragma unroll
    for (int i = 0; i < 8; i++) {
      int r = r0 + ty + i * 8;
      tile[ty + i * 8][tx] = in[(size_t)min(r, R - 1) * HH + k0 + tx];
    }
    __syncthreads();
    const int rl = tid & 63, kcl = tid >> 6;
    bf16x8 ov;
#pragma unroll
    for (int j = 0; j < 8; j++) ov[j] = (short)f2bf(tile[rl][kcl * 8 + j]);
    *(bf16x8*)&o[((size_t)((k0 >> 3) + kcl) * RP + r0 + rl) * 8] = ov;
  } else if (bid < 708) {
    int i = (bid - 408) * 256 + tid;
    if (i < BB * SS * CC * 3) out[i] = b2[i % 3];
  } else {
    const int wb = bid - 708;
    const float* in;
    unsigned short* o;
    int N, bx, by;
    if (wb < 3456) {
      in = W1; o = W1C; N = H4; bx = wb % 48; by = wb / 48;
    } else if (wb < 4032) {
      int b = wb - 3456; in = Wt; o = WtC; N = H2; bx = b % 24; by = b / 24;
    } else {
      int b = wb - 4032; in = Wl; o = WlC; N = H2; bx = b % 24; by = b / 24;
    }
    const int f = bx * 64 + (tid & 63);
    const int hc = by * 4 + (tid >> 6);
    bf16x8 ov;
#pragma unroll
    for (int j = 0; j < 8; j++)
      ov[j] = (short)f2bf(in[(size_t)(hc * 8 + j) * N + f]);
    *(bf16x8*)&o[((size_t)hc * N + f) * 8] = ov;
  }
}

// ---------------- shared K-loop (R9-proven): 128x128, BK=64, 2 barriers ----
DEVINL void mm_kloop(const unsigned short* __restrict__ Ab, int NRA, int MA,
                     int m0, const unsigned short* __restrict__ Bt, int NRB,
                     int n0, unsigned short* As, unsigned short* Bs,
                     f32x4 (&acc)[4][4]) {
  const int tid = threadIdx.x;
  const int lane = tid & 63;
  const int wave = tid >> 6;
  const int q = lane >> 4;
  const int li = lane & 15;
  const int wm = (wave >> 1) * 64;
  const int wn = (wave & 1) * 64;

  int sr[4], skc[4], sra[4];
#pragma unroll
  for (int j = 0; j < 4; j++) {
    int slot = j * 256 + tid;
    skc[j] = slot >> 7;
    sr[j] = slot & 127;
    sra[j] = min(m0 + sr[j], MA - 1);
  }
  auto stage = [&](int kciter) {
#pragma unroll
    for (int j = 0; j < 4; j++) {
      int slot = j * 256 + tid;
      async16(Ab + ((size_t)(kciter + skc[j]) * NRA + sra[j]) * 8,
              (char*)As + slot * 16);
      async16(Bt + ((size_t)(kciter + skc[j]) * NRB + n0 + sr[j]) * 8,
              (char*)Bs + slot * 16);
    }
  };

  stage(0);
  for (int it = 0; it < 12; it++) {
    __syncthreads();  // stage landed
#pragma unroll
    for (int ks = 0; ks < 2; ks++) {
      bf16x8 af[4], bb[4];
#pragma unroll
      for (int mi = 0; mi < 4; mi++)
        af[mi] = *(const bf16x8*)&As[((ks * 4 + q) * 128 + wm + mi * 16 + li) * 8];
#pragma unroll
      for (int ni = 0; ni < 4; ni++)
        bb[ni] = *(const bf16x8*)&Bs[((ks * 4 + q) * 128 + wn + ni * 16 + li) * 8];
#pragma unroll
      for (int mi = 0; mi < 4; mi++)
#pragma unroll
        for (int ni = 0; ni < 4; ni++)
          acc[mi][ni] = __builtin_amdgcn_mfma_f32_16x16x32_bf16(
              af[mi], bb[ni], acc[mi][ni], 0, 0, 0);
    }
    __syncthreads();  // all reads done
    if (it + 1 < 12) stage((it + 1) * 8);
  }
}

// ---------------- K2: G1+G2 fused (108 blocks) ----------------
__global__ __launch_bounds__(256, 4) void k_mm1(
    const unsigned short* __restrict__ TC, const unsigned short* __restrict__ LC,
    const unsigned short* __restrict__ WtC, const unsigned short* __restrict__ WlC,
    const float* __restrict__ bt, const float* __restrict__ bl,
    unsigned short* __restrict__ TP, unsigned short* __restrict__ LP) {
  __shared__ __align__(16) unsigned short As[8 * 128 * 8];
  __shared__ __align__(16) unsigned short Bs[8 * 128 * 8];
  const int bid = blockIdx.x;
  const int nt = bid % 12, my = bid / 12;
  const bool tok = my < 8;
  const unsigned short* A = tok ? TC : LC;
  const unsigned short* Bt = tok ? WtC : WlC;
  const float* bias = tok ? bt : bl;
  unsigned short* C = tok ? TP : LP;
  const int NRA = tok ? 1024 : 64, MA = tok ? 1024 : 50;
  const int m0 = tok ? my * 128 : 0;
  const int ldc = NRA;
  const int n0 = nt * 128;

  f32x4 acc[4][4];
#pragma unroll
  for (int i = 0; i < 4; i++)
#pragma unroll
    for (int j = 0; j < 4; j++) acc[i][j] = (f32x4){0.f, 0.f, 0.f, 0.f};
  mm_kloop(A, NRA, MA, m0, Bt, H2, n0, As, Bs, acc);

  const int lane = threadIdx.x & 63, wave = threadIdx.x >> 6;
  const int q = lane >> 4, li = lane & 15;
  const int wm = (wave >> 1) * 64, wn = (wave & 1) * 64;
#pragma unroll
  for (int mi = 0; mi < 4; mi++)
#pragma unroll
    for (int rr = 0; rr < 4; rr++) {
      int row = m0 + wm + mi * 16 + q * 4 + rr;
      if (row < MA) {
#pragma unroll
        for (int ni = 0; ni < 4; ni++) {
          int col = n0 + wn + ni * 16 + li;
          C[((size_t)(col >> 3) * ldc + row) * 8 + (col & 7)] =
              f2bf(acc[mi][ni][rr] + bias[col]);
        }
      }
    }
}

// ---------------- K3: G3+G4 (216 blocks, bf16 out) + make_x (9600) ----------
__global__ __launch_bounds__(256, 4) void k_mm2(
    const unsigned short* __restrict__ TP, const unsigned short* __restrict__ LP,
    const unsigned short* __restrict__ W1C, const float* __restrict__ b1,
    unsigned short* __restrict__ bbase, unsigned short* __restrict__ albf,
    unsigned short* __restrict__ XC) {
  __shared__ __align__(16) unsigned short As[8 * 128 * 8];
  __shared__ __align__(16) unsigned short Bs[8 * 128 * 8];
  const int bid = blockIdx.x;
  if (bid < 216) {
    const int nt = bid % 24, my = bid / 24;
    const bool tok = my < 8;
    const unsigned short* A = tok ? TP : LP;
    const unsigned short* Bt = tok ? W1C : W1C + (size_t)96 * H4 * 8;
    unsigned short* Cb = tok ? bbase : albf;
    const int NRA = tok ? 1024 : 64, MA = tok ? 1024 : 50;
    const int m0 = tok ? my * 128 : 0;
    const int n0 = nt * 128;

    f32x4 acc[4][4];
#pragma unroll
    for (int i = 0; i < 4; i++)
#pragma unroll
      for (int j = 0; j < 4; j++) acc[i][j] = (f32x4){0.f, 0.f, 0.f, 0.f};
    mm_kloop(A, NRA, MA, m0, Bt, H4, n0, As, Bs, acc);

    const int lane = threadIdx.x & 63, wave = threadIdx.x >> 6;
    const int q = lane >> 4, li = lane & 15;
    const int wm = (wave >> 1) * 64, wn = (wave & 1) * 64;
#pragma unroll
    for (int mi = 0; mi < 4; mi++)
#pragma unroll
      for (int rr = 0; rr < 4; rr++) {
        int row = m0 + wm + mi * 16 + q * 4 + rr;
        if (row < MA) {
#pragma unroll
          for (int ni = 0; ni < 4; ni++) {
            int col = n0 + wn + ni * 16 + li;
            float v = acc[mi][ni][rr] + (tok ? 0.f : b1[col]);  // fold b1 into al
            Cb[(size_t)row * H4 + col] = f2bf(v);
          }
        }
      }
  } else {
    // make_x
    const int i = bid - 216;           // 0..9599
    const int bc = i / 192;
    const int rem = i % 192;
    const int hc = rem >> 1;
    const int s = (rem & 1) * 256 + threadIdx.x;
    const int b = bc / CC;
    bf16x8 tv = *(const bf16x8*)&TP[((size_t)(96 + hc) * 1024 + b * 512 + s) * 8];
    bf16x8 lv = *(const bf16x8*)&LP[((size_t)(96 + hc) * 64 + bc) * 8];
    bf16x8 o;
#pragma unroll
    for (int j = 0; j < 8; j++)
      o[j] = (short)f2bf(bf2f((unsigned short)tv[j]) * bf2f((unsigned short)lv[j]));
    *(bf16x8*)&XC[(size_t)bc * XC_STRIDE + ((size_t)hc * 512 + s) * 8] = o;
  }
}

// ---------------- K4: G5 scorer, 256m x 128n tile, 256 threads --------------
// Wave grid 2m x 2n; wave-tile 128m x 64n; acc[8][4]. LDS 48 KB -> 3 blocks/CU.
// Grid (24 n-tiles, 100 = 50 bc x 2 m-tiles of 256).
__global__ __launch_bounds__(256, 3) void k_scorer(
    const unsigned short* __restrict__ XC,     // per-bc slabs [96][512][8]
    const unsigned short* __restrict__ Bt,     // W1p chunked [96][3072][8]
    const unsigned short* __restrict__ bbase,  // [1024][3072] bf16
    const unsigned short* __restrict__ albf,   // [50][3072] bf16 (incl. b1)
    const float* __restrict__ W2,
    float* __restrict__ out) {
  __shared__ __align__(16) unsigned short As[8 * 256 * 8];  // 32 KB
  __shared__ __align__(16) unsigned short Bs[8 * 128 * 8];  // 16 KB
  const int tid = threadIdx.x;
  const int lane = tid & 63;
  const int wave = tid >> 6;
  const int q = lane >> 4;
  const int li = lane & 15;
  const int wm = (wave >> 1) * 128;   // 0 / 128
  const int wn = (wave & 1) * 64;     // 0 / 64

  const int n0 = blockIdx.x * 128;
  const int bc = blockIdx.y >> 1;
  const int m0 = (blockIdx.y & 1) * 256;
  const unsigned short* Ab = XC + (size_t)bc * XC_STRIDE;

  f32x4 acc[8][4];
#pragma unroll
  for (int i = 0; i < 8; i++)
#pragma unroll
    for (int j = 0; j < 4; j++) acc[i][j] = (f32x4){0.f, 0.f, 0.f, 0.f};

  // staging: A slots j=0..8 (kc=slot>>8, row=slot&255); B slots j=0..4
  auto stage = [&](int kcbase) {
#pragma unroll
    for (int j = 0; j < 8; j++) {
      int slot = j * 256 + tid;
      async16(Ab + ((size_t)(kcbase + (slot >> 8)) * 512 + m0 + (slot & 255)) * 8,
              (char*)As + slot * 16);
    }
#pragma unroll
    for (int j = 0; j < 4; j++) {
      int slot = j * 256 + tid;
      async16(Bt + ((size_t)(kcbase + (slot >> 7)) * H4 + n0 + (slot & 127)) * 8,
              (char*)Bs + slot * 16);
    }
  };

  stage(0);
  for (int it = 0; it < 12; it++) {
    __syncthreads();  // stage landed
#pragma unroll
    for (int ks = 0; ks < 2; ks++) {
      bf16x8 bb[4];
#pragma unroll
      for (int ni = 0; ni < 4; ni++)
        bb[ni] = *(const bf16x8*)&Bs[((ks * 4 + q) * 128 + wn + ni * 16 + li) * 8];
#pragma unroll
      for (int mi = 0; mi < 8; mi++) {
        bf16x8 af = *(const bf16x8*)&As[((ks * 4 + q) * 256 + wm + mi * 16 + li) * 8];
#pragma unroll
        for (int ni = 0; ni < 4; ni++)
          acc[mi][ni] = __builtin_amdgcn_mfma_f32_16x16x32_bf16(
              af, bb[ni], acc[mi][ni], 0, 0, 0);
      }
    }
    __syncthreads();  // all reads done
    if (it + 1 < 12) stage((it + 1) * 8);
  }

  __syncthreads();  // reads done before Ew scratch reuse

  // epilogue: E = acc + base + al(+b1); relu; out += E @ W2 via MFMA
  const int b = bc / CC, c = bc % CC;
  int fcol[4];
  float alb[4];
#pragma unroll
  for (int ni = 0; ni < 4; ni++) {
    int f = n0 + wn + ni * 16 + li;
    fcol[ni] = f;
    alb[ni] = bf2f(albf[(size_t)bc * H4 + f]);
  }
  bf16x8 w2f[2];
#pragma unroll
  for (int ks = 0; ks < 2; ks++)
#pragma unroll
    for (int jj = 0; jj < 8; jj++) {
      int f = n0 + wn + ks * 32 + q * 8 + jj;
      float v = (li < 3) ? W2[(size_t)f * 3 + li] : 0.f;
      w2f[ks][jj] = (short)f2bf(v);
    }
  unsigned short* Ew = (unsigned short*)((char*)As + wave * 2304);

#pragma unroll
  for (int mi = 0; mi < 8; mi++) {
    float bs[4][4];
#pragma unroll
    for (int rr = 0; rr < 4; rr++) {
      int s_l = m0 + wm + mi * 16 + q * 4 + rr;
      const unsigned short* bp = bbase + (size_t)(b * SS + s_l) * H4;
#pragma unroll
      for (int ni = 0; ni < 4; ni++) bs[ni][rr] = bf2f(bp[fcol[ni]]);
    }
#pragma unroll
    for (int rr = 0; rr < 4; rr++)
#pragma unroll
      for (int ni = 0; ni < 4; ni++) {
        float v = acc[mi][ni][rr] + bs[ni][rr] + alb[ni];
        v = fmaxf(v, 0.f);
        Ew[(q * 4 + rr) * 72 + ni * 16 + li] = f2bf(v);
      }
    f32x4 oc = (f32x4){0.f, 0.f, 0.f, 0.f};
#pragma unroll
    for (int ks = 0; ks < 2; ks++) {
      bf16x8 ef = *(const bf16x8*)&Ew[li * 72 + ks * 32 + q * 8];
      oc = __builtin_amdgcn_mfma_f32_16x16x32_bf16(ef, w2f[ks], oc, 0, 0, 0);
    }
#pragma unroll
    for (int rr = 0; rr < 4; rr++) {
      int s_l = m0 + wm + mi * 16 + q * 4 + rr;
      if (li < 3)
        atomicAdd(&out[((size_t)(b * SS + s_l) * CC + c) * 3 + li], oc[rr]);
    }
  }
}

// ---------------- host launch ----------------

extern "C" void kernel_launch(void* const* d_in, const int* in_sizes, int n_in,
                              void* d_out, int out_size, void* d_ws, size_t ws_size,
                              hipStream_t stream) {
  (void)in_sizes; (void)n_in; (void)ws_size; (void)out_size;
  const float* token = (const float*)d_in[0];
  const float* label = (const float*)d_in[1];
  const float* Wt    = (const float*)d_in[2];
  const float* bt    = (const float*)d_in[3];
  const float* Wl    = (const float*)d_in[4];
  const float* bl    = (const float*)d_in[5];
  const float* W1    = (const float*)d_in[6];
  const float* b1    = (const float*)d_in[7];
  const float* W2    = (const float*)d_in[8];
  const float* b2    = (const float*)d_in[9];
  float* out = (float*)d_out;

  char* p = (char*)d_ws;
  auto alloc = [&](size_t bytes) {
    char* r = p;
    p += (bytes + 255) & ~(size_t)255;
    return r;
  };
  unsigned short* TC  = (unsigned short*)alloc((size_t)96 * 1024 * 8 * 2);
  unsigned short* LC  = (unsigned short*)alloc((size_t)96 * 64 * 8 * 2);
  unsigned short* WtC = (unsigned short*)alloc((size_t)96 * 1536 * 8 * 2);
  unsigned short* WlC = (unsigned short*)alloc((size_t)96 * 1536 * 8 * 2);
  unsigned short* W1C = (unsigned short*)alloc((size_t)288 * 3072 * 8 * 2);
  unsigned short* TP  = (unsigned short*)alloc((size_t)192 * 1024 * 8 * 2);
  unsigned short* LP  = (unsigned short*)alloc((size_t)192 * 64 * 8 * 2);
  unsigned short* XC  = (unsigned short*)alloc((size_t)CC * BB * XC_STRIDE * 2);
  unsigned short* bbase = (unsigned short*)alloc((size_t)BB * SS * H4 * 2);
  unsigned short* albf  = (unsigned short*)alloc((size_t)BB * CC * H4 * 2);

  // K1: all casts/chunking + out init
  k_prep<<<5316, 256, 0, stream>>>(token, label, b2, Wt, Wl, W1,
                                   TC, LC, out, WtC, WlC, W1C);
  // K2: G1+G2 fused projections
  k_mm1<<<108, 256, 0, stream>>>(TC, LC, WtC, WlC, bt, bl, TP, LP);
  // K3: G3+G4 GEMMs (bf16 out, b1 folded into al) + make_x
  k_mm2<<<9816, 256, 0, stream>>>(TP, LP, W1C, b1, bbase, albf, XC);
  // K4: G5 scorer, 256x128 tiles
  k_scorer<<<dim3(24, 100), 256, 0, stream>>>(
      XC, W1C + (size_t)192 * H4 * 8, bbase, albf, W2, out);
}

// Round 12
// 279.166 us; speedup vs baseline: 1.4042x; 1.4042x over previous
//
#include <hip/hip_runtime.h>
#include <hip/hip_bf16.h>
#include <cstdint>
#include <cstddef>

// Shapes: B=2, S=512, C=25, H=768, 2H=1536, 3H=2304, 4H=3072
#define BB 2
#define SS 512
#define CC 25
#define HH 768
#define H2 1536
#define H3 2304
#define H4 3072
// chunked layout: [kc][row][8] bf16, kc = k/8
#define XC_STRIDE ((size_t)96 * 512 * 8)   // per-bc X slab, 96 chunks x 512 rows

typedef __attribute__((ext_vector_type(8))) short bf16x8;
typedef __attribute__((ext_vector_type(4))) float f32x4;

#define DEVINL static __device__ __forceinline__

DEVINL unsigned short f2bf(float f) {
  union { float f; unsigned u; } v; v.f = f;
  unsigned r = v.u + 0x7FFF + ((v.u >> 16) & 1);  // RNE
  return (unsigned short)(r >> 16);
}
DEVINL float bf2f(unsigned short b) {
  union { unsigned u; float f; } v; v.u = ((unsigned)b) << 16; return v.f;
}

DEVINL void async16(const void* g, void* l) {
  __builtin_amdgcn_global_load_lds(
      (const __attribute__((address_space(1))) void*)g,
      (__attribute__((address_space(3))) void*)l, 16, 0, 0);
}

// ---------------- K1: all casts/chunking + out init (5316 blocks) ----------
__global__ void k_prep(const float* __restrict__ token,
                       const float* __restrict__ label,
                       const float* __restrict__ b2,
                       const float* __restrict__ Wt,
                       const float* __restrict__ Wl,
                       const float* __restrict__ W1,
                       unsigned short* __restrict__ TC,
                       unsigned short* __restrict__ LC,
                       float* __restrict__ out,
                       unsigned short* __restrict__ WtC,
                       unsigned short* __restrict__ WlC,
                       unsigned short* __restrict__ W1C) {
  __shared__ float tile[64][33];
  const int bid = blockIdx.x;
  const int tid = threadIdx.x;
  if (bid < 408) {
    const float* in;
    unsigned short* o;
    int R, RP, kt, rt;
    if (bid < 384) {
      in = token; o = TC; R = 1024; RP = 1024; kt = bid % 24; rt = bid / 24;
    } else {
      in = label; o = LC; R = 50; RP = 64; kt = bid - 384; rt = 0;
    }
    const int k0 = kt * 32, r0 = rt * 64;
    const int tx = tid & 31, ty = tid >> 5;
#pragma unroll
    for (int i = 0; i < 8; i++) {
      int r = r0 + ty + i * 8;
      tile[ty + i * 8][tx] = in[(size_t)min(r, R - 1) * HH + k0 + tx];
    }
    __syncthreads();
    const int rl = tid & 63, kcl = tid >> 6;
    bf16x8 ov;
#pragma unroll
    for (int j = 0; j < 8; j++) ov[j] = (short)f2bf(tile[rl][kcl * 8 + j]);
    *(bf16x8*)&o[((size_t)((k0 >> 3) + kcl) * RP + r0 + rl) * 8] = ov;
  } else if (bid < 708) {
    int i = (bid - 408) * 256 + tid;
    if (i < BB * SS * CC * 3) out[i] = b2[i % 3];
  } else {
    const int wb = bid - 708;
    const float* in;
    unsigned short* o;
    int N, bx, by;
    if (wb < 3456) {
      in = W1; o = W1C; N = H4; bx = wb % 48; by = wb / 48;
    } else if (wb < 4032) {
      int b = wb - 3456; in = Wt; o = WtC; N = H2; bx = b % 24; by = b / 24;
    } else {
      int b = wb - 4032; in = Wl; o = WlC; N = H2; bx = b % 24; by = b / 24;
    }
    const int f = bx * 64 + (tid & 63);
    const int hc = by * 4 + (tid >> 6);
    bf16x8 ov;
#pragma unroll
    for (int j = 0; j < 8; j++)
      ov[j] = (short)f2bf(in[(size_t)(hc * 8 + j) * N + f]);
    *(bf16x8*)&o[((size_t)hc * N + f) * 8] = ov;
  }
}

// ---------------- shared K-loop (R9-proven): 128x128, BK=64, 2 barriers ----
DEVINL void mm_kloop(const unsigned short* __restrict__ Ab, int NRA, int MA,
                     int m0, const unsigned short* __restrict__ Bt, int NRB,
                     int n0, unsigned short* As, unsigned short* Bs,
                     f32x4 (&acc)[4][4]) {
  const int tid = threadIdx.x;
  const int lane = tid & 63;
  const int wave = tid >> 6;
  const int q = lane >> 4;
  const int li = lane & 15;
  const int wm = (wave >> 1) * 64;
  const int wn = (wave & 1) * 64;

  int sr[4], skc[4], sra[4];
#pragma unroll
  for (int j = 0; j < 4; j++) {
    int slot = j * 256 + tid;
    skc[j] = slot >> 7;
    sr[j] = slot & 127;
    sra[j] = min(m0 + sr[j], MA - 1);
  }
  auto stage = [&](int kciter) {
#pragma unroll
    for (int j = 0; j < 4; j++) {
      int slot = j * 256 + tid;
      async16(Ab + ((size_t)(kciter + skc[j]) * NRA + sra[j]) * 8,
              (char*)As + slot * 16);
      async16(Bt + ((size_t)(kciter + skc[j]) * NRB + n0 + sr[j]) * 8,
              (char*)Bs + slot * 16);
    }
  };

  stage(0);
  for (int it = 0; it < 12; it++) {
    __syncthreads();  // stage landed
#pragma unroll
    for (int ks = 0; ks < 2; ks++) {
      bf16x8 af[4], bb[4];
#pragma unroll
      for (int mi = 0; mi < 4; mi++)
        af[mi] = *(const bf16x8*)&As[((ks * 4 + q) * 128 + wm + mi * 16 + li) * 8];
#pragma unroll
      for (int ni = 0; ni < 4; ni++)
        bb[ni] = *(const bf16x8*)&Bs[((ks * 4 + q) * 128 + wn + ni * 16 + li) * 8];
#pragma unroll
      for (int mi = 0; mi < 4; mi++)
#pragma unroll
        for (int ni = 0; ni < 4; ni++)
          acc[mi][ni] = __builtin_amdgcn_mfma_f32_16x16x32_bf16(
              af[mi], bb[ni], acc[mi][ni], 0, 0, 0);
    }
    __syncthreads();  // all reads done
    if (it + 1 < 12) stage((it + 1) * 8);
  }
}

// ---------------- K2: G1+G2 fused (108 blocks) ----------------
__global__ __launch_bounds__(256, 4) void k_mm1(
    const unsigned short* __restrict__ TC, const unsigned short* __restrict__ LC,
    const unsigned short* __restrict__ WtC, const unsigned short* __restrict__ WlC,
    const float* __restrict__ bt, const float* __restrict__ bl,
    unsigned short* __restrict__ TP, unsigned short* __restrict__ LP) {
  __shared__ __align__(16) unsigned short As[8 * 128 * 8];
  __shared__ __align__(16) unsigned short Bs[8 * 128 * 8];
  const int bid = blockIdx.x;
  const int nt = bid % 12, my = bid / 12;
  const bool tok = my < 8;
  const unsigned short* A = tok ? TC : LC;
  const unsigned short* Bt = tok ? WtC : WlC;
  const float* bias = tok ? bt : bl;
  unsigned short* C = tok ? TP : LP;
  const int NRA = tok ? 1024 : 64, MA = tok ? 1024 : 50;
  const int m0 = tok ? my * 128 : 0;
  const int ldc = NRA;
  const int n0 = nt * 128;

  f32x4 acc[4][4];
#pragma unroll
  for (int i = 0; i < 4; i++)
#pragma unroll
    for (int j = 0; j < 4; j++) acc[i][j] = (f32x4){0.f, 0.f, 0.f, 0.f};
  mm_kloop(A, NRA, MA, m0, Bt, H2, n0, As, Bs, acc);

  const int lane = threadIdx.x & 63, wave = threadIdx.x >> 6;
  const int q = lane >> 4, li = lane & 15;
  const int wm = (wave >> 1) * 64, wn = (wave & 1) * 64;
#pragma unroll
  for (int mi = 0; mi < 4; mi++)
#pragma unroll
    for (int rr = 0; rr < 4; rr++) {
      int row = m0 + wm + mi * 16 + q * 4 + rr;
      if (row < MA) {
#pragma unroll
        for (int ni = 0; ni < 4; ni++) {
          int col = n0 + wn + ni * 16 + li;
          C[((size_t)(col >> 3) * ldc + row) * 8 + (col & 7)] =
              f2bf(acc[mi][ni][rr] + bias[col]);
        }
      }
    }
}

// ---------------- K3: G3+G4 (216 blocks, bf16 out) + make_x (9600) ----------
__global__ __launch_bounds__(256, 4) void k_mm2(
    const unsigned short* __restrict__ TP, const unsigned short* __restrict__ LP,
    const unsigned short* __restrict__ W1C, const float* __restrict__ b1,
    unsigned short* __restrict__ bbase, unsigned short* __restrict__ albf,
    unsigned short* __restrict__ XC) {
  __shared__ __align__(16) unsigned short As[8 * 128 * 8];
  __shared__ __align__(16) unsigned short Bs[8 * 128 * 8];
  const int bid = blockIdx.x;
  if (bid < 216) {
    const int nt = bid % 24, my = bid / 24;
    const bool tok = my < 8;
    const unsigned short* A = tok ? TP : LP;
    const unsigned short* Bt = tok ? W1C : W1C + (size_t)96 * H4 * 8;
    unsigned short* Cb = tok ? bbase : albf;
    const int NRA = tok ? 1024 : 64, MA = tok ? 1024 : 50;
    const int m0 = tok ? my * 128 : 0;
    const int n0 = nt * 128;

    f32x4 acc[4][4];
#pragma unroll
    for (int i = 0; i < 4; i++)
#pragma unroll
      for (int j = 0; j < 4; j++) acc[i][j] = (f32x4){0.f, 0.f, 0.f, 0.f};
    mm_kloop(A, NRA, MA, m0, Bt, H4, n0, As, Bs, acc);

    const int lane = threadIdx.x & 63, wave = threadIdx.x >> 6;
    const int q = lane >> 4, li = lane & 15;
    const int wm = (wave >> 1) * 64, wn = (wave & 1) * 64;
#pragma unroll
    for (int mi = 0; mi < 4; mi++)
#pragma unroll
      for (int rr = 0; rr < 4; rr++) {
        int row = m0 + wm + mi * 16 + q * 4 + rr;
        if (row < MA) {
#pragma unroll
          for (int ni = 0; ni < 4; ni++) {
            int col = n0 + wn + ni * 16 + li;
            float v = acc[mi][ni][rr] + (tok ? 0.f : b1[col]);  // fold b1 into al
            Cb[(size_t)row * H4 + col] = f2bf(v);
          }
        }
      }
  } else {
    // make_x
    const int i = bid - 216;           // 0..9599
    const int bc = i / 192;
    const int rem = i % 192;
    const int hc = rem >> 1;
    const int s = (rem & 1) * 256 + threadIdx.x;
    const int b = bc / CC;
    bf16x8 tv = *(const bf16x8*)&TP[((size_t)(96 + hc) * 1024 + b * 512 + s) * 8];
    bf16x8 lv = *(const bf16x8*)&LP[((size_t)(96 + hc) * 64 + bc) * 8];
    bf16x8 o;
#pragma unroll
    for (int j = 0; j < 8; j++)
      o[j] = (short)f2bf(bf2f((unsigned short)tv[j]) * bf2f((unsigned short)lv[j]));
    *(bf16x8*)&XC[(size_t)bc * XC_STRIDE + ((size_t)hc * 512 + s) * 8] = o;
  }
}

// ---------------- K4: G5 scorer (R9 config: 128x128, grid 24 x 200) ---------
__global__ __launch_bounds__(256, 4) void k_scorer(
    const unsigned short* __restrict__ XC,     // per-bc slabs [96][512][8]
    const unsigned short* __restrict__ Bt,     // W1p chunked [96][3072][8]
    const unsigned short* __restrict__ bbase,  // [1024][3072] bf16
    const unsigned short* __restrict__ albf,   // [50][3072] bf16 (incl. b1)
    const float* __restrict__ W2,
    float* __restrict__ out) {
  __shared__ __align__(16) unsigned short As[8 * 128 * 8];
  __shared__ __align__(16) unsigned short Bs[8 * 128 * 8];
  const int tid = threadIdx.x;
  const int lane = tid & 63;
  const int wave = tid >> 6;
  const int q = lane >> 4;
  const int li = lane & 15;
  const int wm = (wave >> 1) * 64;
  const int wn = (wave & 1) * 64;

  const int n0 = blockIdx.x * 128;
  const int bc = blockIdx.y >> 2;
  const int m0 = (blockIdx.y & 3) * 128;
  const unsigned short* Ab = XC + (size_t)bc * XC_STRIDE;

  f32x4 acc[4][4];
#pragma unroll
  for (int i = 0; i < 4; i++)
#pragma unroll
    for (int j = 0; j < 4; j++) acc[i][j] = (f32x4){0.f, 0.f, 0.f, 0.f};
  mm_kloop(Ab, 512, 512, m0, Bt, H4, n0, As, Bs, acc);

  __syncthreads();  // all LDS buffer reads done before Ew scratch reuse

  // epilogue: E = acc + base + al(+b1); relu; out += E @ W2 via MFMA
  const int b = bc / CC, c = bc % CC;
  int fcol[4];
  float alb[4];
#pragma unroll
  for (int ni = 0; ni < 4; ni++) {
    int f = n0 + wn + ni * 16 + li;
    fcol[ni] = f;
    alb[ni] = bf2f(albf[(size_t)bc * H4 + f]);
  }
  bf16x8 w2f[2];
#pragma unroll
  for (int ks = 0; ks < 2; ks++)
#pragma unroll
    for (int jj = 0; jj < 8; jj++) {
      int f = n0 + wn + ks * 32 + q * 8 + jj;
      float v = (li < 3) ? W2[(size_t)f * 3 + li] : 0.f;
      w2f[ks][jj] = (short)f2bf(v);
    }
  unsigned short* Ew = (unsigned short*)((char*)As + wave * 2304);

#pragma unroll
  for (int mi = 0; mi < 4; mi++) {
    float bs[4][4];
#pragma unroll
    for (int rr = 0; rr < 4; rr++) {
      int s_l = m0 + wm + mi * 16 + q * 4 + rr;
      const unsigned short* bp = bbase + (size_t)(b * SS + s_l) * H4;
#pragma unroll
      for (int ni = 0; ni < 4; ni++) bs[ni][rr] = bf2f(bp[fcol[ni]]);
    }
#pragma unroll
    for (int rr = 0; rr < 4; rr++)
#pragma unroll
      for (int ni = 0; ni < 4; ni++) {
        float v = acc[mi][ni][rr] + bs[ni][rr] + alb[ni];
        v = fmaxf(v, 0.f);
        Ew[(q * 4 + rr) * 72 + ni * 16 + li] = f2bf(v);
      }
    f32x4 oc = (f32x4){0.f, 0.f, 0.f, 0.f};
#pragma unroll
    for (int ks = 0; ks < 2; ks++) {
      bf16x8 ef = *(const bf16x8*)&Ew[li * 72 + ks * 32 + q * 8];
      oc = __builtin_amdgcn_mfma_f32_16x16x32_bf16(ef, w2f[ks], oc, 0, 0, 0);
    }
#pragma unroll
    for (int rr = 0; rr < 4; rr++) {
      int s_l = m0 + wm + mi * 16 + q * 4 + rr;
      if (li < 3)
        atomicAdd(&out[((size_t)(b * SS + s_l) * CC + c) * 3 + li], oc[rr]);
    }
  }
}

// ---------------- host launch ----------------

extern "C" void kernel_launch(void* const* d_in, const int* in_sizes, int n_in,
                              void* d_out, int out_size, void* d_ws, size_t ws_size,
                              hipStream_t stream) {
  (void)in_sizes; (void)n_in; (void)ws_size; (void)out_size;
  const float* token = (const float*)d_in[0];
  const float* label = (const float*)d_in[1];
  const float* Wt    = (const float*)d_in[2];
  const float* bt    = (const float*)d_in[3];
  const float* Wl    = (const float*)d_in[4];
  const float* bl    = (const float*)d_in[5];
  const float* W1    = (const float*)d_in[6];
  const float* b1    = (const float*)d_in[7];
  const float* W2    = (const float*)d_in[8];
  const float* b2    = (const float*)d_in[9];
  float* out = (float*)d_out;

  char* p = (char*)d_ws;
  auto alloc = [&](size_t bytes) {
    char* r = p;
    p += (bytes + 255) & ~(size_t)255;
    return r;
  };
  unsigned short* TC  = (unsigned short*)alloc((size_t)96 * 1024 * 8 * 2);
  unsigned short* LC  = (unsigned short*)alloc((size_t)96 * 64 * 8 * 2);
  unsigned short* WtC = (unsigned short*)alloc((size_t)96 * 1536 * 8 * 2);
  unsigned short* WlC = (unsigned short*)alloc((size_t)96 * 1536 * 8 * 2);
  unsigned short* W1C = (unsigned short*)alloc((size_t)288 * 3072 * 8 * 2);
  unsigned short* TP  = (unsigned short*)alloc((size_t)192 * 1024 * 8 * 2);
  unsigned short* LP  = (unsigned short*)alloc((size_t)192 * 64 * 8 * 2);
  unsigned short* XC  = (unsigned short*)alloc((size_t)CC * BB * XC_STRIDE * 2);
  unsigned short* bbase = (unsigned short*)alloc((size_t)BB * SS * H4 * 2);
  unsigned short* albf  = (unsigned short*)alloc((size_t)BB * CC * H4 * 2);

  // K1: all casts/chunking + out init
  k_prep<<<5316, 256, 0, stream>>>(token, label, b2, Wt, Wl, W1,
                                   TC, LC, out, WtC, WlC, W1C);
  // K2: G1+G2 fused projections
  k_mm1<<<108, 256, 0, stream>>>(TC, LC, WtC, WlC, bt, bl, TP, LP);
  // K3: G3+G4 GEMMs (bf16 out, b1 folded into al) + make_x
  k_mm2<<<9816, 256, 0, stream>>>(TP, LP, W1C, b1, bbase, albf, XC);
  // K4: G5 scorer (R9-proven 128x128 config)
  k_scorer<<<dim3(24, 200), 256, 0, stream>>>(
      XC, W1C + (size_t)192 * H4 * 8, bbase, albf, W2, out);
}